// Round 1
// baseline (1038961.133 us; speedup 1.0000x reference)
//
#include <hip/hip_runtime.h>
#include <hip/hip_bf16.h>
#include <math.h>

// Problem constants
#define VV   32000
#define DD   300
#define HU   300
#define NC   3
#define BB   128
#define TT   512
#define N4H  1200
#define CHUNK 64
#define NCHUNK (TT / CHUNK)

// Recurrent kernel partition
#define GC   15   // col groups (units)
#define GR   16   // row groups
#define RPW  8    // rows per WG (BB/GR)
#define UPW  20   // units per WG (HU/GC)
#define KSW  96   // k-window per wave (4 waves x 96 covers 300 w/ zero pad)
#define HLB_STRIDE 312            // h plane row stride in shorts (624B: 16B-aligned, 2-way bank alias = free)
#define HLB_SIZE   (16 * HLB_STRIDE + 32)

// Workspace layout: [zx (float)][ex (ulong, tagged h exchange)][cst][hfin][prb][prb2][okt]
static constexpr size_t ZX_F   = (size_t)BB * CHUNK * N4H;   // 9,830,400 floats
static constexpr size_t EX_W   = (size_t)2 * GR * RPW * HU;  // 76,800 ulongs
static constexpr size_t CST_F  = (size_t)BB * HU;            // 38,400 floats
static constexpr size_t HFIN_F = (size_t)BB * HU;            // 38,400 floats
static constexpr size_t PRB_W  = (size_t)GR * GC;            // 240 ulongs (x3 tables)

typedef __attribute__((ext_vector_type(8))) short bf16x8;
typedef __attribute__((ext_vector_type(8))) _Float16 f16x8;
typedef __attribute__((ext_vector_type(4))) float f32x4;
typedef unsigned long long ull;

__device__ __forceinline__ short f2bf(float f) {
    unsigned u = __float_as_uint(f);
    u += 0x7fff + ((u >> 16) & 1);   // round-to-nearest-even
    return (short)(u >> 16);
}
__device__ __forceinline__ short f2h(float f) {   // float -> f16 bits (RTNE)
    _Float16 h = (_Float16)f;
    return *(short*)&h;
}
__device__ __forceinline__ float h2f(short s) {
    _Float16 h = *(_Float16*)&s;
    return (float)h;
}
__device__ __forceinline__ float sigm(float x) { return 1.f / (1.f + __expf(-x)); }
__device__ __forceinline__ float tanh_(float x) { return 1.f - 2.f / (__expf(2.f * x) + 1.f); }

// ---------------------------------------------------------------------------
// init: zero exchange tags, c state, out[0]  (ws is poisoned 0xAA every launch)
// prb/prb2/okt need no init: they are dispatch-tagged (t0+1 never matches
// poison 0xAAAAAAAA or a previous dispatch's tag).
// ---------------------------------------------------------------------------
__global__ void init_kernel(ull* __restrict__ ex, float* __restrict__ cst,
                            float* __restrict__ out) {
    size_t i = (size_t)blockIdx.x * 256 + threadIdx.x;
    if (i < EX_W) ex[i] = 0ull;
    if (i < CST_F) cst[i] = 0.f;
    if (i == 0) out[0] = 0.f;
}

// ---------------------------------------------------------------------------
// Phase 1: zx[b][tc][n] = emb[ids[b][t0+tc]] @ W_lstm[0:300] + b_lstm   (bf16 MFMA)
// WG tile: M=256 rows, N=80 cols, K=320 (300 zero-padded). 4 waves, wave = 64x80.
// grid = (8192/256, 1200/80) = (32, 15)
// ---------------------------------------------------------------------------
__global__ __launch_bounds__(256) void zx_gemm(
    const float* __restrict__ emb, const int* __restrict__ ids,
    const float* __restrict__ Wl, const float* __restrict__ bl,
    float* __restrict__ zx, int t0)
{
    __shared__ short A_l[256 * 40];   // [row][k] pad 32->40 shorts
    __shared__ short B_l[80 * 40];    // [col][k] (transposed)
    __shared__ int   ids_l[256];

    const int tid = threadIdx.x;
    const int m0  = blockIdx.x * 256;
    const int n0  = blockIdx.y * 80;
    const int wv  = tid >> 6, ln = tid & 63;

    {   // per-row embedding id
        int m = m0 + tid;
        int b = m >> 6, tc = m & (CHUNK - 1);
        ids_l[tid] = ids[b * TT + t0 + tc];
    }

    f32x4 acc[4][5];
    for (int i = 0; i < 4; ++i)
        for (int j = 0; j < 5; ++j)
            acc[i][j] = (f32x4){0.f, 0.f, 0.f, 0.f};

    for (int k0 = 0; k0 < 320; k0 += 32) {
        __syncthreads();
        // stage A: 256 rows x 32 k, one row per thread (float4 x8, guard k<300)
        {
            const float* src = emb + (size_t)ids_l[tid] * DD;
            #pragma unroll
            for (int q = 0; q < 8; ++q) {
                int kg = k0 + q * 4;
                float4 v;
                if (kg < DD) v = *(const float4*)(src + kg);
                else         v = make_float4(0.f, 0.f, 0.f, 0.f);
                short4 s; s.x = f2bf(v.x); s.y = f2bf(v.y); s.z = f2bf(v.z); s.w = f2bf(v.w);
                *(short4*)&A_l[tid * 40 + q * 4] = s;
            }
        }
        // stage B (transposed): 80 cols x 32 k. thread: kk=tid>>3, 10 cols each
        {
            int kk = tid >> 3;
            int c0 = (tid & 7) * 10;
            int kg = k0 + kk;
            #pragma unroll
            for (int c = 0; c < 10; ++c) {
                float v = (kg < DD) ? Wl[(size_t)kg * N4H + n0 + c0 + c] : 0.f;
                B_l[(c0 + c) * 40 + kk] = f2bf(v);
            }
        }
        __syncthreads();
        // fragments + MFMA. A[m=lane&15][k=quad*8+j], B[k=quad*8+j][n=lane&15]
        const int koff = (ln >> 4) * 8;
        bf16x8 afr[4], bfr[5];
        #pragma unroll
        for (int mt = 0; mt < 4; ++mt) {
            int row = wv * 64 + mt * 16 + (ln & 15);
            afr[mt] = *(const bf16x8*)&A_l[row * 40 + koff];
        }
        #pragma unroll
        for (int nt = 0; nt < 5; ++nt) {
            int col = nt * 16 + (ln & 15);
            bfr[nt] = *(const bf16x8*)&B_l[col * 40 + koff];
        }
        #pragma unroll
        for (int mt = 0; mt < 4; ++mt)
            #pragma unroll
            for (int nt = 0; nt < 5; ++nt)
                acc[mt][nt] = __builtin_amdgcn_mfma_f32_16x16x32_bf16(
                    afr[mt], bfr[nt], acc[mt][nt], 0, 0, 0);
    }
    // epilogue: C row=(lane>>4)*4+reg, col=lane&15; add bias
    #pragma unroll
    for (int mt = 0; mt < 4; ++mt) {
        #pragma unroll
        for (int nt = 0; nt < 5; ++nt) {
            #pragma unroll
            for (int rg = 0; rg < 4; ++rg) {
                int row = m0 + wv * 64 + mt * 16 + (ln >> 4) * 4 + rg;
                int col = n0 + nt * 16 + (ln & 15);
                zx[(size_t)row * N4H + col] = acc[mt][nt][rg] + bl[col];
            }
        }
    }
}

// ---------------------------------------------------------------------------
// Phase 2: persistent recurrent kernel. 240 WGs = 16 row-groups x 15 col-groups.
// Recurrent GEMM: F16 MFMA with h-side split (absmax at 4.88e-4 output floor):
//   z = (h_hi + h_lo) @ W_f16,  h_hi = f16(h), h_lo = f16(h - h_hi)
// W_h f16 fragments live in LDS, fragment-ordered (R10). Per-wave K-window
// waiting + single barrier per step (R11). Sentinel-gated polling (R12).
//
// R13: SAME-XCD L2 EXCHANGE. With round-robin WG->XCD dispatch, a row-group's
// 15 WGs (blockIdx = rg + 16*cgi, XCD = blockIdx%8 = rg%8) share ONE XCD and
// therefore ONE L2. Agent-scope atomics route every exchange leg through the
// cross-XCD coherence point (LLC/fabric) — both the latency (~1000+cyc/leg)
// and the sustained ~1.1 TB/s of sweep reads that R12's post-mortem showed
// inflating every round trip. Plain stores (CDNA L1 is write-through -> land
// in L2) + sc0 loads (bypass L1, served by the shared L2) keep all exchange
// traffic XCD-local at ~200-400cyc/leg.
//   Safety: correctness must NOT depend on XCD placement (G16). Per dispatch,
// each WG plain-stores a dispatch-tagged probe carrying its HW_REG_XCC_ID
// (+ an agent-scope copy); partners poll via sc0 with a bounded spin and an
// agent side-channel that fast-fails cross-XCD placement; the 15 WGs then
// agree on a single l2m flag through agent atomics. l2m=0 -> exact R12 agent
// path. Even a false-positive cannot hang: in-step spins escape to agent
// loads after 2048 iterations (accept from either path).
//   Also R13: producer pre-splits h into the f16 hi/lo pair and publishes
// [tag:32|lo:16|hi:16] — consumers do 2 bit-extracts instead of 2 f16
// conversions + subtract per word. Bit-identical within a dispatch; the
// cross-dispatch reload reconstructs hi+lo (~1e-7 vs exact f32).
//
// Tag-ABA safety unchanged (transitive, per-wave): publish(s+2) > barrier(s+1)
// > all 4 waves detected tags s+1 over window-union = all 15 producers'
// s+1 publishes >= every consumer's step-s reads.
//
// NaN guard (R6): both h planes zeroed IN FULL once per dispatch, so wave 3's
// A reads of cols 300..319 are exact 0 (B=0 there; 0*0=0).
// ---------------------------------------------------------------------------
__global__ __launch_bounds__(256, 1) void lstm_rec(
    const float* __restrict__ zx, const float* __restrict__ Wl,
    const int* __restrict__ lens, ull* __restrict__ ex,
    float* __restrict__ cst, float* __restrict__ hfin,
    ull* __restrict__ prb, ull* __restrict__ prb2, ull* __restrict__ okt,
    int t0)
{
    const int tid = threadIdx.x;
    const int wv  = tid >> 6, ln = tid & 63;
    const int rg  = blockIdx.x % GR;
    const int cgi = blockIdx.x / GR;
    const int r0  = rg * RPW;
    const int u0  = cgi * UPW;
    const int m   = ln & 15;           // MFMA row / col-in-tile
    const int quad = ln >> 4;

    // producers overlapping wave wv's K-window [96wv, 96wv+96)
    const int pstart_tbl[4] = {0, 4, 9, 14};
    const int np_tbl[4]     = {5, 6, 6, 1};
    const int pstart = pstart_tbl[wv];
    const int np     = np_tbl[wv];

    __shared__ short h_hi[HLB_SIZE];        // f16 hi plane of h_{t-1}
    __shared__ short h_lo[HLB_SIZE];        // f16 lo plane of h_{t-1}
    __shared__ float zp[2][4][RPW][84];     // parity x wave k-partials (pad 80->84)
    __shared__ short w_l[4 * 15 * 64 * 8];  // f16 W_h fragments, frag-ordered
    __shared__ int   l2flag;                // 1 = row-group co-XCD, use L2 path

    // ---- R13 probe store ASAP: dispatch-tagged, carries our XCC_ID ----
    // HW_REG_XCC_ID = hwreg 20, offset 0, width 4 -> simm16 = 20 | (3<<11) = 6164
    const unsigned ptag = (unsigned)(t0 + 1);
    if (tid == 0) {
        unsigned myx = __builtin_amdgcn_s_getreg(6164) & 0xFu;
        ull pv = ((ull)ptag << 32) | ((ull)myx << 8) | 1ull;
        const ull* pp = prb + rg * GC + cgi;
        asm volatile("global_store_dwordx2 %0, %1, off" :: "v"(pp), "v"(pv) : "memory");
        __hip_atomic_store(prb2 + rg * GC + cgi, pv,
                           __ATOMIC_RELAXED, __HIP_MEMORY_SCOPE_AGENT);
    }

    // ---- one-time: pack W_h f16 B-fragments into LDS ----
    // B[k=quad*8+j][n=lane&15]; frag f = s*5+nt covers kstep s, ntile nt.
    #pragma unroll
    for (int s = 0; s < 3; ++s) {
        #pragma unroll
        for (int nt = 0; nt < 5; ++nt) {
            int c    = nt * 16 + m;            // 0..79 within WG cols
            int gate = c / 20;
            int wcol = 300 * gate + u0 + (c % 20);
            f16x8 b;
            #pragma unroll
            for (int j = 0; j < 8; ++j) {
                int k = KSW * wv + 32 * s + quad * 8 + j;
                float v = (k < HU) ? Wl[(size_t)(DD + k) * N4H + wcol] : 0.f;
                b[j] = (_Float16)v;
            }
            *(f16x8*)&w_l[(((wv * 15) + (s * 5 + nt)) * 64 + ln) * 8] = b;
        }
    }
    const int nks = (wv == 3) ? 1 : 3;   // wave 3: only kstep 0 has real k

    // zero BOTH h planes in full once per dispatch (NaN guard + h0 = 0)
    for (int i = tid; i < HLB_SIZE; i += 256) { h_hi[i] = 0; h_lo[i] = 0; }

    // gate role (tid < 160): u = tid%20, r = tid/20; c/h_old in registers
    const int g_u = tid % UPW, g_r = tid / UPW;
    const bool gl = (tid < RPW * UPW);
    float c_reg = 0.f, ho_reg = 0.f;
    int mylen = 0;
    if (gl) {
        c_reg = cst[(size_t)(r0 + g_r) * HU + u0 + g_u];
        mylen = lens[r0 + g_r];
        if (t0 > 0) {   // reload own h_{t0-1} (tag t0, parity t0&1) from last dispatch
            ull v = __hip_atomic_load(
                ex + (((size_t)(t0 & 1) * GR + rg) * RPW + g_r) * HU + u0 + g_u,
                __ATOMIC_RELAXED, __HIP_MEMORY_SCOPE_AGENT);
            unsigned d = (unsigned)v;
            ho_reg = h2f((short)(d & 0xFFFFu)) + h2f((short)(d >> 16));
        }
    }

    // ---- R13 probe poll: wave 0, lane l watches partner l ----
    if (wv == 0) {
        unsigned myx = __builtin_amdgcn_s_getreg(6164) & 0xFu;
        bool okl = true;
        if (ln < GC) {
            okl = false;
            const ull* pp  = prb  + rg * GC + ln;
            const ull* pp2 = prb2 + rg * GC + ln;
            for (int it = 0; it < 4000; ++it) {
                ull v;
                asm volatile("global_load_dwordx2 %0, %1, off sc0\n\ts_waitcnt vmcnt(0)"
                             : "=v"(v) : "v"(pp) : "memory");
                if ((unsigned)(v >> 32) == ptag) {          // seen via L2 path
                    okl = (((v >> 8) & 0xFull) == myx);
                    break;
                }
                if ((it & 7) == 7) {                         // agent side channel
                    ull w = __hip_atomic_load(pp2, __ATOMIC_RELAXED,
                                              __HIP_MEMORY_SCOPE_AGENT);
                    if ((unsigned)(w >> 32) == ptag &&
                        ((w >> 8) & 0xFull) != myx) { okl = false; break; }
                }
                __builtin_amdgcn_s_sleep(4);
            }
        }
        ull bal = __ballot(okl);
        if (ln == 0) {
            int mine = (bal == ~0ull) ? 1 : 0;
            __hip_atomic_store(okt + rg * GC + cgi,
                               ((ull)ptag << 32) | (unsigned)mine,
                               __ATOMIC_RELAXED, __HIP_MEMORY_SCOPE_AGENT);
            int good = 1;
            for (int p = 0; p < GC; ++p) {
                ull v;
                while (true) {
                    v = __hip_atomic_load(okt + rg * GC + p, __ATOMIC_RELAXED,
                                          __HIP_MEMORY_SCOPE_AGENT);
                    if ((unsigned)(v >> 32) == ptag) break;
                    __builtin_amdgcn_s_sleep(8);
                }
                good &= (int)(v & 1);
            }
            l2flag = good;
        }
    }
    __syncthreads();   // h-plane zero + w_l pack + l2flag visible before first step
    const bool l2m = (l2flag != 0);

    for (int tc = 0; tc < CHUNK; ++tc) {
        const int t = t0 + tc;
        const int par = t & 1;

        // prefetch zx for this step (independent of h)
        float z_pre[4];
        if (gl) {
            const float* zrow = zx + ((size_t)(r0 + g_r) * CHUNK + tc) * N4H;
            #pragma unroll
            for (int gg = 0; gg < 4; ++gg)
                z_pre[gg] = zrow[300 * gg + u0 + g_u];
        }

        // ---- per-wave stage of OWN K-window stripe (no barrier after) ----
        if (t > 0) {
            const ull* exb = ex + ((size_t)par * GR + rg) * (RPW * HU);

            // phase 1: sentinel spin — lane l polls producer pstart+l (word
            // r=0, u=20p). Cheap (<=6 lines/wave/sweep vs 96 for a full pass).
            if (ln < np) {
                const ull* sp = exb + (pstart + ln) * UPW;
                if (l2m) {
                    int spins = 0;
                    while (true) {
                        ull v;
                        asm volatile("global_load_dwordx2 %0, %1, off sc0\n\ts_waitcnt vmcnt(0)"
                                     : "=v"(v) : "v"(sp) : "memory");
                        if ((int)(v >> 32) >= t) break;
                        if (++spins > 2048) {   // escape hatch (false-positive l2m)
                            ull w = __hip_atomic_load(sp, __ATOMIC_RELAXED,
                                                      __HIP_MEMORY_SCOPE_AGENT);
                            if ((int)(w >> 32) >= t) break;
                        }
                        __builtin_amdgcn_s_sleep(1);
                    }
                } else {
                    while ((int)(__hip_atomic_load(sp, __ATOMIC_RELAXED,
                                 __HIP_MEMORY_SCOPE_AGENT) >> 32) < t)
                        __builtin_amdgcn_s_sleep(1);
                }
            }

            // phase 2+3: full stripe pass (typically 1 sweep) + straggler poll
            if (wv < 3) {
                // 768 words: i = ln + 64k, r = i/96, u = 96*wv + i%96
                unsigned pend = 0xFFFu;
                if (l2m) {
                    int spins = 0;
                    do {
                        ull v[12] = {};
                        #pragma unroll
                        for (int k = 0; k < 12; ++k)
                            if ((pend >> k) & 1) {
                                int i = ln + (k << 6);
                                int r = i / 96, u = KSW * wv + (i % 96);
                                asm volatile("global_load_dwordx2 %0, %1, off sc0"
                                             : "=v"(v[k]) : "v"(exb + r * HU + u));
                            }
                        asm volatile("s_waitcnt vmcnt(0)"
                                     : "+v"(v[0]), "+v"(v[1]), "+v"(v[2]), "+v"(v[3]),
                                       "+v"(v[4]), "+v"(v[5]), "+v"(v[6]), "+v"(v[7]),
                                       "+v"(v[8]), "+v"(v[9]), "+v"(v[10]), "+v"(v[11])
                                     :: "memory");
                        if (++spins > 2048) {   // escape hatch
                            #pragma unroll
                            for (int k = 0; k < 12; ++k)
                                if (((pend >> k) & 1) && (int)(v[k] >> 32) < t) {
                                    int i = ln + (k << 6);
                                    int r = i / 96, u = KSW * wv + (i % 96);
                                    v[k] = __hip_atomic_load(exb + r * HU + u,
                                             __ATOMIC_RELAXED, __HIP_MEMORY_SCOPE_AGENT);
                                }
                        }
                        unsigned got = 0;
                        #pragma unroll
                        for (int k = 0; k < 12; ++k) {
                            if (((pend >> k) & 1) && (int)(v[k] >> 32) >= t) {
                                int i = ln + (k << 6);
                                int r = i / 96, u = KSW * wv + (i % 96);
                                int idx = r * HLB_STRIDE + u;
                                unsigned d = (unsigned)v[k];
                                h_hi[idx] = (short)(d & 0xFFFFu);
                                h_lo[idx] = (short)(d >> 16);
                                got |= 1u << k;
                            }
                        }
                        pend &= ~got;
                        if (pend) __builtin_amdgcn_s_sleep(1);
                    } while (pend);
                } else {
                    do {
                        ull v[12];
                        #pragma unroll
                        for (int k = 0; k < 12; ++k)
                            if ((pend >> k) & 1) {
                                int i = ln + (k << 6);
                                int r = i / 96, u = KSW * wv + (i % 96);
                                v[k] = __hip_atomic_load(exb + r * HU + u,
                                                         __ATOMIC_RELAXED,
                                                         __HIP_MEMORY_SCOPE_AGENT);
                            }
                        unsigned got = 0;
                        #pragma unroll
                        for (int k = 0; k < 12; ++k) {
                            if (((pend >> k) & 1) && (int)(v[k] >> 32) >= t) {
                                int i = ln + (k << 6);
                                int r = i / 96, u = KSW * wv + (i % 96);
                                int idx = r * HLB_STRIDE + u;
                                unsigned d = (unsigned)v[k];
                                h_hi[idx] = (short)(d & 0xFFFFu);
                                h_lo[idx] = (short)(d >> 16);
                                got |= 1u << k;
                            }
                        }
                        pend &= ~got;
                        if (pend) __builtin_amdgcn_s_sleep(1);
                    } while (pend);
                }
            } else {
                // 96 words: i = ln + 64k (i<96), r = i/12, u = 288 + i%12
                unsigned pend = (ln < 32) ? 0x3u : 0x1u;
                if (l2m) {
                    int spins = 0;
                    do {
                        ull v[2] = {};
                        #pragma unroll
                        for (int k = 0; k < 2; ++k)
                            if ((pend >> k) & 1) {
                                int i = ln + (k << 6);
                                int r = i / 12, u = 288 + (i % 12);
                                asm volatile("global_load_dwordx2 %0, %1, off sc0"
                                             : "=v"(v[k]) : "v"(exb + r * HU + u));
                            }
                        asm volatile("s_waitcnt vmcnt(0)"
                                     : "+v"(v[0]), "+v"(v[1]) :: "memory");
                        if (++spins > 2048) {
                            #pragma unroll
                            for (int k = 0; k < 2; ++k)
                                if (((pend >> k) & 1) && (int)(v[k] >> 32) < t) {
                                    int i = ln + (k << 6);
                                    int r = i / 12, u = 288 + (i % 12);
                                    v[k] = __hip_atomic_load(exb + r * HU + u,
                                             __ATOMIC_RELAXED, __HIP_MEMORY_SCOPE_AGENT);
                                }
                        }
                        unsigned got = 0;
                        #pragma unroll
                        for (int k = 0; k < 2; ++k) {
                            if (((pend >> k) & 1) && (int)(v[k] >> 32) >= t) {
                                int i = ln + (k << 6);
                                int r = i / 12, u = 288 + (i % 12);
                                int idx = r * HLB_STRIDE + u;
                                unsigned d = (unsigned)v[k];
                                h_hi[idx] = (short)(d & 0xFFFFu);
                                h_lo[idx] = (short)(d >> 16);
                                got |= 1u << k;
                            }
                        }
                        pend &= ~got;
                        if (pend) __builtin_amdgcn_s_sleep(1);
                    } while (pend);
                } else {
                    do {
                        ull v[2];
                        #pragma unroll
                        for (int k = 0; k < 2; ++k)
                            if ((pend >> k) & 1) {
                                int i = ln + (k << 6);
                                int r = i / 12, u = 288 + (i % 12);
                                v[k] = __hip_atomic_load(exb + r * HU + u,
                                                         __ATOMIC_RELAXED,
                                                         __HIP_MEMORY_SCOPE_AGENT);
                            }
                        unsigned got = 0;
                        #pragma unroll
                        for (int k = 0; k < 2; ++k) {
                            if (((pend >> k) & 1) && (int)(v[k] >> 32) >= t) {
                                int i = ln + (k << 6);
                                int r = i / 12, u = 288 + (i % 12);
                                int idx = r * HLB_STRIDE + u;
                                unsigned d = (unsigned)v[k];
                                h_hi[idx] = (short)(d & 0xFFFFu);
                                h_lo[idx] = (short)(d >> 16);
                                got |= 1u << k;
                            }
                        }
                        pend &= ~got;
                        if (pend) __builtin_amdgcn_s_sleep(1);
                    } while (pend);
                }
            }
        }

        // ---- MFMA on own stripe: A hi/lo from LDS, B f16 from LDS ----
        f32x4 acc[5];
        #pragma unroll
        for (int nt = 0; nt < 5; ++nt) acc[nt] = (f32x4){0.f, 0.f, 0.f, 0.f};
        for (int s = 0; s < nks; ++s) {
            const int aoff = m * HLB_STRIDE + KSW * wv + 32 * s + quad * 8;
            f16x8 ah = *(const f16x8*)&h_hi[aoff];
            f16x8 al = *(const f16x8*)&h_lo[aoff];
            f16x8 bfr[5];
            #pragma unroll
            for (int nt = 0; nt < 5; ++nt)
                bfr[nt] = *(const f16x8*)&w_l[(((wv * 15) + (s * 5 + nt)) * 64 + ln) * 8];
            #pragma unroll
            for (int nt = 0; nt < 5; ++nt)
                acc[nt] = __builtin_amdgcn_mfma_f32_16x16x32_f16(
                    ah, bfr[nt], acc[nt], 0, 0, 0);
            #pragma unroll
            for (int nt = 0; nt < 5; ++nt)
                acc[nt] = __builtin_amdgcn_mfma_f32_16x16x32_f16(
                    al, bfr[nt], acc[nt], 0, 0, 0);
        }
        // C: row=quad*4+reg (lanes 0-31 -> rows 0-7), col=nt*16+m
        if (ln < 32) {
            #pragma unroll
            for (int nt = 0; nt < 5; ++nt)
                #pragma unroll
                for (int r4 = 0; r4 < 4; ++r4)
                    zp[par][wv][quad * 4 + r4][nt * 16 + m] = acc[nt][r4];
        }
        __syncthreads();   // the ONE barrier: zp(t) visible to gate lanes

        // ---- reduce 4 partials + gates + tagged publish (160 threads) ----
        if (gl) {
            const int b = r0 + g_r;
            float z4[4];
            #pragma unroll
            for (int gg = 0; gg < 4; ++gg) {
                int cidx = gg * UPW + g_u;
                z4[gg] = z_pre[gg] + zp[par][0][g_r][cidx] + zp[par][1][g_r][cidx]
                                   + zp[par][2][g_r][cidx] + zp[par][3][g_r][cidx];
            }
            float ig = sigm(z4[0]);
            float jg = tanh_(z4[1]);
            float fg = sigm(z4[2] + 1.0f);   // FORGET_BIAS
            float og = sigm(z4[3]);
            float c_new = c_reg * fg + ig * jg;
            float h_new = tanh_(c_new) * og;
            bool upd = (t < mylen);
            ho_reg = upd ? h_new : ho_reg;
            c_reg  = upd ? c_new : c_reg;
            // publish h_t (tag t+1, parity (t+1)&1), producer-side hi/lo split:
            // [tag:32 | lo:16 | hi:16] — fire & forget
            short hhi = f2h(ho_reg);
            short hlo = f2h(ho_reg - h2f(hhi));
            ull pk = ((ull)(unsigned)(t + 1) << 32)
                   | ((ull)(unsigned short)hlo << 16) | (ull)(unsigned short)hhi;
            ull* dst = ex + (((size_t)((t + 1) & 1) * GR + rg) * RPW + g_r) * HU + u0 + g_u;
            if (l2m) {
                asm volatile("global_store_dwordx2 %0, %1, off" :: "v"(dst), "v"(pk) : "memory");
            } else {
                __hip_atomic_store(dst, pk, __ATOMIC_RELAXED, __HIP_MEMORY_SCOPE_AGENT);
            }
            if (tc == CHUNK - 1) hfin[(size_t)b * HU + u0 + g_u] = ho_reg;
        }
        // no trailing barrier: per-wave detect + the single barrier order all
        // h-stripe and zp reuse (see header proof).
    }
    if (gl) cst[(size_t)(r0 + g_r) * HU + u0 + g_u] = c_reg;
    // l2m-mode plain stores of the final step are flushed to memory at
    // dispatch end (same mechanism hfin/cst already rely on), so the next
    // dispatch's agent-scope reload sees them.
}

// ---------------------------------------------------------------------------
// Phase 3: logits = h_final @ W_dense + b_dense; log-softmax NLL; mean loss.
// One wave per batch row.
// ---------------------------------------------------------------------------
__global__ __launch_bounds__(64) void cls_kernel(
    const float* __restrict__ hfin, const float* __restrict__ Wd,
    const float* __restrict__ bd, const int* __restrict__ labels,
    float* __restrict__ out)
{
    const int b = blockIdx.x;
    const int ln = threadIdx.x;
    const float* h = hfin + (size_t)b * HU;
    float p0 = 0.f, p1 = 0.f, p2 = 0.f;
    for (int k = ln; k < HU; k += 64) {
        float hv = h[k];
        p0 += hv * Wd[k * 3 + 0];
        p1 += hv * Wd[k * 3 + 1];
        p2 += hv * Wd[k * 3 + 2];
    }
    #pragma unroll
    for (int off = 32; off > 0; off >>= 1) {
        p0 += __shfl_down(p0, off);
        p1 += __shfl_down(p1, off);
        p2 += __shfl_down(p2, off);
    }
    if (ln == 0) {
        float l0 = p0 + bd[0], l1 = p1 + bd[1], l2 = p2 + bd[2];
        float m = fmaxf(l0, fmaxf(l1, l2));
        float lse = m + logf(__expf(l0 - m) + __expf(l1 - m) + __expf(l2 - m));
        int lab = labels[b];
        float sel = (lab == 0) ? l0 : ((lab == 1) ? l1 : l2);
        float nll = lse - sel;
        out[1 + b * 3 + 0] = l0;
        out[1 + b * 3 + 1] = l1;
        out[1 + b * 3 + 2] = l2;
        atomicAdd(out, nll * (1.0f / BB));
    }
}

// ---------------------------------------------------------------------------
extern "C" void kernel_launch(void* const* d_in, const int* in_sizes, int n_in,
                              void* d_out, int out_size, void* d_ws, size_t ws_size,
                              hipStream_t stream) {
    const int*   ids  = (const int*)d_in[0];
    const int*   lens = (const int*)d_in[1];
    const int*   labs = (const int*)d_in[2];
    const float* emb  = (const float*)d_in[3];
    const float* Wl   = (const float*)d_in[4];
    const float* bl   = (const float*)d_in[5];
    const float* Wd   = (const float*)d_in[6];
    const float* bd   = (const float*)d_in[7];
    float* out = (float*)d_out;

    float* zx   = (float*)d_ws;
    ull*   ex   = (ull*)(zx + ZX_F);
    float* cst  = (float*)(ex + EX_W);
    float* hfin = cst + CST_F;
    ull*   prb  = (ull*)(hfin + HFIN_F);
    ull*   prb2 = prb + PRB_W;
    ull*   okt  = prb2 + PRB_W;

    {   // zero exchange tags / c state / out[0]
        int n = (int)((EX_W + 255) / 256);
        init_kernel<<<n, 256, 0, stream>>>(ex, cst, out);
    }
    for (int c = 0; c < NCHUNK; ++c) {
        int t0 = c * CHUNK;
        zx_gemm<<<dim3(32, 15), 256, 0, stream>>>(emb, ids, Wl, bl, zx, t0);
        lstm_rec<<<GR * GC, 256, 0, stream>>>(zx, Wl, lens, ex, cst, hfin,
                                              prb, prb2, okt, t0);
    }
    cls_kernel<<<BB, 64, 0, stream>>>(hfin, Wd, bd, labs, out);
}

// Round 2
// 3301.662 us; speedup vs baseline: 314.6782x; 314.6782x over previous
//
#include <hip/hip_runtime.h>
#include <hip/hip_bf16.h>
#include <math.h>

// Problem constants
#define VV   32000
#define DD   300
#define HU   300
#define NC   3
#define BB   128
#define TT   512
#define N4H  1200
#define CHUNK 64
#define NCHUNK (TT / CHUNK)

// Recurrent kernel partition
#define GC   15   // col groups (units)
#define GR   16   // row groups
#define RPW  8    // rows per WG (BB/GR)
#define UPW  20   // units per WG (HU/GC)
#define KSW  96   // k-window per wave (4 waves x 96 covers 300 w/ zero pad)
#define HLB_STRIDE 312            // h plane row stride in shorts (624B: 16B-aligned, 2-way bank alias = free)
#define HLB_SIZE   (16 * HLB_STRIDE + 32)

// Workspace layout: [zx (float)][exv (u32 values)][ext (u32 tags)][cst][hfin]
static constexpr size_t ZX_F   = (size_t)BB * CHUNK * N4H;   // 9,830,400 floats
static constexpr size_t EXV_W  = (size_t)2 * GR * RPW * HU;  // 76,800 u32 (4B/unit: [lo16|hi16])
static constexpr size_t EXT_W  = (size_t)2 * GR * GC * 4;    // 1,920 u32 (per-wave tags, stride 4)
static constexpr size_t CST_F  = (size_t)BB * HU;            // 38,400 floats
static constexpr size_t HFIN_F = (size_t)BB * HU;            // 38,400 floats

typedef __attribute__((ext_vector_type(8))) short bf16x8;
typedef __attribute__((ext_vector_type(8))) _Float16 f16x8;
typedef __attribute__((ext_vector_type(4))) float f32x4;
typedef unsigned long long ull;

__device__ __forceinline__ short f2bf(float f) {
    unsigned u = __float_as_uint(f);
    u += 0x7fff + ((u >> 16) & 1);   // round-to-nearest-even
    return (short)(u >> 16);
}
__device__ __forceinline__ short f2h(float f) {   // float -> f16 bits (RTNE)
    _Float16 h = (_Float16)f;
    return *(short*)&h;
}
__device__ __forceinline__ float h2f(short s) {
    _Float16 h = *(_Float16*)&s;
    return (float)h;
}
__device__ __forceinline__ float sigm(float x) { return 1.f / (1.f + __expf(-x)); }
__device__ __forceinline__ float tanh_(float x) { return 1.f - 2.f / (__expf(2.f * x) + 1.f); }

// ---------------------------------------------------------------------------
// init: zero tag table, c state, out[0]  (ws is poisoned 0xAA every launch)
// exv needs NO init: consumers only read value words after the owning wave's
// tag (stored strictly after a vmcnt(0) fence over the value stores) reads >= t.
// ---------------------------------------------------------------------------
__global__ void init_kernel(unsigned* __restrict__ ext, float* __restrict__ cst,
                            float* __restrict__ out) {
    size_t i = (size_t)blockIdx.x * 256 + threadIdx.x;
    if (i < EXT_W) ext[i] = 0u;
    if (i < CST_F) cst[i] = 0.f;
    if (i == 0) out[0] = 0.f;
}

// ---------------------------------------------------------------------------
// Phase 1: zx[b][tc][n] = emb[ids[b][t0+tc]] @ W_lstm[0:300] + b_lstm   (bf16 MFMA)
// WG tile: M=256 rows, N=80 cols, K=320 (300 zero-padded). 4 waves, wave = 64x80.
// grid = (8192/256, 1200/80) = (32, 15)
// ---------------------------------------------------------------------------
__global__ __launch_bounds__(256) void zx_gemm(
    const float* __restrict__ emb, const int* __restrict__ ids,
    const float* __restrict__ Wl, const float* __restrict__ bl,
    float* __restrict__ zx, int t0)
{
    __shared__ short A_l[256 * 40];   // [row][k] pad 32->40 shorts
    __shared__ short B_l[80 * 40];    // [col][k] (transposed)
    __shared__ int   ids_l[256];

    const int tid = threadIdx.x;
    const int m0  = blockIdx.x * 256;
    const int n0  = blockIdx.y * 80;
    const int wv  = tid >> 6, ln = tid & 63;

    {   // per-row embedding id
        int m = m0 + tid;
        int b = m >> 6, tc = m & (CHUNK - 1);
        ids_l[tid] = ids[b * TT + t0 + tc];
    }

    f32x4 acc[4][5];
    for (int i = 0; i < 4; ++i)
        for (int j = 0; j < 5; ++j)
            acc[i][j] = (f32x4){0.f, 0.f, 0.f, 0.f};

    for (int k0 = 0; k0 < 320; k0 += 32) {
        __syncthreads();
        // stage A: 256 rows x 32 k, one row per thread (float4 x8, guard k<300)
        {
            const float* src = emb + (size_t)ids_l[tid] * DD;
            #pragma unroll
            for (int q = 0; q < 8; ++q) {
                int kg = k0 + q * 4;
                float4 v;
                if (kg < DD) v = *(const float4*)(src + kg);
                else         v = make_float4(0.f, 0.f, 0.f, 0.f);
                short4 s; s.x = f2bf(v.x); s.y = f2bf(v.y); s.z = f2bf(v.z); s.w = f2bf(v.w);
                *(short4*)&A_l[tid * 40 + q * 4] = s;
            }
        }
        // stage B (transposed): 80 cols x 32 k. thread: kk=tid>>3, 10 cols each
        {
            int kk = tid >> 3;
            int c0 = (tid & 7) * 10;
            int kg = k0 + kk;
            #pragma unroll
            for (int c = 0; c < 10; ++c) {
                float v = (kg < DD) ? Wl[(size_t)kg * N4H + n0 + c0 + c] : 0.f;
                B_l[(c0 + c) * 40 + kk] = f2bf(v);
            }
        }
        __syncthreads();
        // fragments + MFMA. A[m=lane&15][k=quad*8+j], B[k=quad*8+j][n=lane&15]
        const int koff = (ln >> 4) * 8;
        bf16x8 afr[4], bfr[5];
        #pragma unroll
        for (int mt = 0; mt < 4; ++mt) {
            int row = wv * 64 + mt * 16 + (ln & 15);
            afr[mt] = *(const bf16x8*)&A_l[row * 40 + koff];
        }
        #pragma unroll
        for (int nt = 0; nt < 5; ++nt) {
            int col = nt * 16 + (ln & 15);
            bfr[nt] = *(const bf16x8*)&B_l[col * 40 + koff];
        }
        #pragma unroll
        for (int mt = 0; mt < 4; ++mt)
            #pragma unroll
            for (int nt = 0; nt < 5; ++nt)
                acc[mt][nt] = __builtin_amdgcn_mfma_f32_16x16x32_bf16(
                    afr[mt], bfr[nt], acc[mt][nt], 0, 0, 0);
    }
    // epilogue: C row=(lane>>4)*4+reg, col=lane&15; add bias
    #pragma unroll
    for (int mt = 0; mt < 4; ++mt) {
        #pragma unroll
        for (int nt = 0; nt < 5; ++nt) {
            #pragma unroll
            for (int rg = 0; rg < 4; ++rg) {
                int row = m0 + wv * 64 + mt * 16 + (ln >> 4) * 4 + rg;
                int col = n0 + nt * 16 + (ln & 15);
                zx[(size_t)row * N4H + col] = acc[mt][nt][rg] + bl[col];
            }
        }
    }
}

// ---------------------------------------------------------------------------
// Phase 2: persistent recurrent kernel. 240 WGs = 16 row-groups x 15 col-groups.
// Recurrent GEMM: F16 MFMA with h-side split (absmax at 4.88e-4 output floor):
//   z = (h_hi + h_lo) @ W_f16,  h_hi = f16(h), h_lo = f16(h - h_hi)
// W_h f16 fragments in LDS (R10); per-wave K-windows + single barrier (R11).
//
// R13 POST-MORTEM: same-XCD L2 exchange (sc0 loads) is DEAD — stale reads
// proved the row-group's WGs are NOT co-XCD under this scheduler, and the
// XCC_ID self-test false-positived (uniform reads). Reverted to agent scope.
//
// R14: WAVE-GRANULAR RELEASE PROTOCOL (replaces R12's per-word tags):
//   publish:  gate lanes store untagged 4B values [lo16|hi16] (relaxed agent)
//             -> s_waitcnt vmcnt(0)  (values acked at coherence point)
//             -> lane 0 of each gl wave stores a 4B per-wave tag = t+1.
//   consume:  spin on the <=3 tags of each producer overlapping this wave's
//             K-window (<=18 tag words/wave), then ONE untagged bulk sweep:
//             6 x dwordx2 per lane (pairs of adjacent units). Half the fabric
//             bytes, half the messages, no per-word tag VALU, no straggler
//             machinery. Producer-side hi/lo split: consumers bit-extract.
//   ordering: tag(W,t+1) visible => W's value stores visible (vmcnt fence) =>
//             standard agent-release. ABA unchanged (transitive, per-wave):
//             publish(s+2) > barrier(s+1) > all 4 waves saw all-15 tags s+1
//             >= every consumer's step-s value loads completed (loads precede
//             the MFMA that precedes the barrier that precedes tag s+1).
//
// NaN guard (R6): both h planes zeroed IN FULL once per dispatch, so wave 3's
// A reads of cols 300..319 are exact 0 (B=0 there; 0*0=0).
// ---------------------------------------------------------------------------
__global__ __launch_bounds__(256, 1) void lstm_rec(
    const float* __restrict__ zx, const float* __restrict__ Wl,
    const int* __restrict__ lens, unsigned* __restrict__ exv,
    unsigned* __restrict__ ext, float* __restrict__ cst,
    float* __restrict__ hfin, int t0)
{
    const int tid = threadIdx.x;
    const int wv  = tid >> 6, ln = tid & 63;
    const int rg  = blockIdx.x % GR;
    const int cgi = blockIdx.x / GR;
    const int r0  = rg * RPW;
    const int u0  = cgi * UPW;
    const int m   = ln & 15;           // MFMA row / col-in-tile
    const int quad = ln >> 4;

    // producers overlapping wave wv's K-window [96wv, 96wv+96)
    const int pstart_tbl[4] = {0, 4, 9, 14};
    const int np_tbl[4]     = {5, 6, 6, 1};
    const int pstart = pstart_tbl[wv];
    const int np     = np_tbl[wv];

    __shared__ __align__(16) short h_hi[HLB_SIZE];  // f16 hi plane of h_{t-1}
    __shared__ __align__(16) short h_lo[HLB_SIZE];  // f16 lo plane of h_{t-1}
    __shared__ float zp[2][4][RPW][84];     // parity x wave k-partials (pad 80->84)
    __shared__ short w_l[4 * 15 * 64 * 8];  // f16 W_h fragments, frag-ordered

    // ---- one-time: pack W_h f16 B-fragments into LDS ----
    // B[k=quad*8+j][n=lane&15]; frag f = s*5+nt covers kstep s, ntile nt.
    #pragma unroll
    for (int s = 0; s < 3; ++s) {
        #pragma unroll
        for (int nt = 0; nt < 5; ++nt) {
            int c    = nt * 16 + m;            // 0..79 within WG cols
            int gate = c / 20;
            int wcol = 300 * gate + u0 + (c % 20);
            f16x8 b;
            #pragma unroll
            for (int j = 0; j < 8; ++j) {
                int k = KSW * wv + 32 * s + quad * 8 + j;
                float v = (k < HU) ? Wl[(size_t)(DD + k) * N4H + wcol] : 0.f;
                b[j] = (_Float16)v;
            }
            *(f16x8*)&w_l[(((wv * 15) + (s * 5 + nt)) * 64 + ln) * 8] = b;
        }
    }
    const int nks = (wv == 3) ? 1 : 3;   // wave 3: only kstep 0 has real k

    // zero BOTH h planes in full once per dispatch (NaN guard + h0 = 0)
    for (int i = tid; i < HLB_SIZE; i += 256) { h_hi[i] = 0; h_lo[i] = 0; }

    // gate role (tid < 160): u = tid%20, r = tid/20; c/h_old in registers
    const int g_u = tid % UPW, g_r = tid / UPW;
    const bool gl = (tid < RPW * UPW);
    float c_reg = 0.f, ho_reg = 0.f;
    int mylen = 0;
    if (gl) {
        c_reg = cst[(size_t)(r0 + g_r) * HU + u0 + g_u];
        mylen = lens[r0 + g_r];
        if (t0 > 0) {   // reload own h_{t0-1} (parity t0&1) from last dispatch
            unsigned v = __hip_atomic_load(
                exv + (((size_t)(t0 & 1) * GR + rg) * RPW + g_r) * HU + u0 + g_u,
                __ATOMIC_RELAXED, __HIP_MEMORY_SCOPE_AGENT);
            ho_reg = h2f((short)(v & 0xFFFFu)) + h2f((short)(v >> 16));
        }
    }
    __syncthreads();   // h-plane zero + w_l pack visible before first step

    for (int tc = 0; tc < CHUNK; ++tc) {
        const int t = t0 + tc;
        const int par = t & 1;

        // prefetch zx for this step (independent of h)
        float z_pre[4];
        if (gl) {
            const float* zrow = zx + ((size_t)(r0 + g_r) * CHUNK + tc) * N4H;
            #pragma unroll
            for (int gg = 0; gg < 4; ++gg)
                z_pre[gg] = zrow[300 * gg + u0 + g_u];
        }

        // ---- per-wave stage of OWN K-window stripe (no barrier after) ----
        if (t > 0) {
            const unsigned* evb = exv + ((size_t)par * GR + rg) * (RPW * HU);
            const unsigned* etb = ext + ((size_t)par * GR + rg) * (GC * 4);

            // phase 1: tag spin — lane l polls tag (producer, wave) = (pstart
            // + l/3, l%3). Tag >= t proves that producer-wave's step-(t-1)
            // value stores are agent-visible (vmcnt-fenced release).
            if (ln < np * 3) {
                int p = pstart + ln / 3;
                int w = ln - 3 * (ln / 3);
                const unsigned* tp = etb + p * 4 + w;
                while (__hip_atomic_load(tp, __ATOMIC_RELAXED,
                                         __HIP_MEMORY_SCOPE_AGENT) < (unsigned)t)
                    __builtin_amdgcn_s_sleep(1);
            }

            // phase 2: ONE untagged bulk sweep, pairs of adjacent units.
            if (wv < 3) {
                // 768 words: even i = 2*ln + 128k, r = i/96, u = 96wv + i%96
                ull v[6];
                #pragma unroll
                for (int k = 0; k < 6; ++k) {
                    int i = 2 * ln + (k << 7);
                    int r = i / 96, u = KSW * wv + (i % 96);
                    v[k] = __hip_atomic_load((const ull*)(evb + r * HU + u),
                                             __ATOMIC_RELAXED,
                                             __HIP_MEMORY_SCOPE_AGENT);
                }
                #pragma unroll
                for (int k = 0; k < 6; ++k) {
                    int i = 2 * ln + (k << 7);
                    int r = i / 96, u = KSW * wv + (i % 96);
                    int idx = r * HLB_STRIDE + u;      // even: 4B LDS stores ok
                    unsigned v0 = (unsigned)v[k], v1 = (unsigned)(v[k] >> 32);
                    *(unsigned*)&h_hi[idx] = (v0 & 0xFFFFu) | (v1 << 16);
                    *(unsigned*)&h_lo[idx] = (v0 >> 16) | (v1 & 0xFFFF0000u);
                }
            } else if (ln < 48) {
                // 96 words: even i = 2*ln, r = i/12, u = 288 + i%12
                int i = 2 * ln;
                int r = i / 12, u = 288 + (i % 12);
                ull v = __hip_atomic_load((const ull*)(evb + r * HU + u),
                                          __ATOMIC_RELAXED,
                                          __HIP_MEMORY_SCOPE_AGENT);
                int idx = r * HLB_STRIDE + u;
                unsigned v0 = (unsigned)v, v1 = (unsigned)(v >> 32);
                *(unsigned*)&h_hi[idx] = (v0 & 0xFFFFu) | (v1 << 16);
                *(unsigned*)&h_lo[idx] = (v0 >> 16) | (v1 & 0xFFFF0000u);
            }
        }

        // ---- MFMA on own stripe: A hi/lo from LDS, B f16 from LDS ----
        f32x4 acc[5];
        #pragma unroll
        for (int nt = 0; nt < 5; ++nt) acc[nt] = (f32x4){0.f, 0.f, 0.f, 0.f};
        for (int s = 0; s < nks; ++s) {
            const int aoff = m * HLB_STRIDE + KSW * wv + 32 * s + quad * 8;
            f16x8 ah = *(const f16x8*)&h_hi[aoff];
            f16x8 al = *(const f16x8*)&h_lo[aoff];
            f16x8 bfr[5];
            #pragma unroll
            for (int nt = 0; nt < 5; ++nt)
                bfr[nt] = *(const f16x8*)&w_l[(((wv * 15) + (s * 5 + nt)) * 64 + ln) * 8];
            #pragma unroll
            for (int nt = 0; nt < 5; ++nt)
                acc[nt] = __builtin_amdgcn_mfma_f32_16x16x32_f16(
                    ah, bfr[nt], acc[nt], 0, 0, 0);
            #pragma unroll
            for (int nt = 0; nt < 5; ++nt)
                acc[nt] = __builtin_amdgcn_mfma_f32_16x16x32_f16(
                    al, bfr[nt], acc[nt], 0, 0, 0);
        }
        // C: row=quad*4+reg (lanes 0-31 -> rows 0-7), col=nt*16+m
        if (ln < 32) {
            #pragma unroll
            for (int nt = 0; nt < 5; ++nt)
                #pragma unroll
                for (int r4 = 0; r4 < 4; ++r4)
                    zp[par][wv][quad * 4 + r4][nt * 16 + m] = acc[nt][r4];
        }
        __syncthreads();   // the ONE barrier: zp(t) visible to gate lanes

        // ---- reduce 4 partials + gates + release-publish (160 threads) ----
        if (gl) {
            const int b = r0 + g_r;
            float z4[4];
            #pragma unroll
            for (int gg = 0; gg < 4; ++gg) {
                int cidx = gg * UPW + g_u;
                z4[gg] = z_pre[gg] + zp[par][0][g_r][cidx] + zp[par][1][g_r][cidx]
                                   + zp[par][2][g_r][cidx] + zp[par][3][g_r][cidx];
            }
            float ig = sigm(z4[0]);
            float jg = tanh_(z4[1]);
            float fg = sigm(z4[2] + 1.0f);   // FORGET_BIAS
            float og = sigm(z4[3]);
            float c_new = c_reg * fg + ig * jg;
            float h_new = tanh_(c_new) * og;
            bool upd = (t < mylen);
            ho_reg = upd ? h_new : ho_reg;
            c_reg  = upd ? c_new : c_reg;
            // value store: [lo16|hi16] untagged, parity (t+1)&1
            short hhi = f2h(ho_reg);
            short hlo = f2h(ho_reg - h2f(hhi));
            unsigned val = ((unsigned)(unsigned short)hlo << 16)
                         | (unsigned)(unsigned short)hhi;
            __hip_atomic_store(
                exv + (((size_t)((t + 1) & 1) * GR + rg) * RPW + g_r) * HU + u0 + g_u,
                val, __ATOMIC_RELAXED, __HIP_MEMORY_SCOPE_AGENT);
            if (tc == CHUNK - 1) hfin[(size_t)b * HU + u0 + g_u] = ho_reg;
            // release fence: values acked at coherence point, THEN the tag.
            asm volatile("s_waitcnt vmcnt(0)" ::: "memory");
            if (ln == 0)   // lane 0 of each gl wave (wv = 0,1,2)
                __hip_atomic_store(
                    ext + (((size_t)((t + 1) & 1) * GR + rg) * GC + cgi) * 4 + wv,
                    (unsigned)(t + 1), __ATOMIC_RELAXED, __HIP_MEMORY_SCOPE_AGENT);
        }
        // no trailing barrier: per-wave tag detect + the single barrier order
        // all h-stripe and zp reuse (see header proof).
    }
    if (gl) cst[(size_t)(r0 + g_r) * HU + u0 + g_u] = c_reg;
}

// ---------------------------------------------------------------------------
// Phase 3: logits = h_final @ W_dense + b_dense; log-softmax NLL; mean loss.
// One wave per batch row.
// ---------------------------------------------------------------------------
__global__ __launch_bounds__(64) void cls_kernel(
    const float* __restrict__ hfin, const float* __restrict__ Wd,
    const float* __restrict__ bd, const int* __restrict__ labels,
    float* __restrict__ out)
{
    const int b = blockIdx.x;
    const int ln = threadIdx.x;
    const float* h = hfin + (size_t)b * HU;
    float p0 = 0.f, p1 = 0.f, p2 = 0.f;
    for (int k = ln; k < HU; k += 64) {
        float hv = h[k];
        p0 += hv * Wd[k * 3 + 0];
        p1 += hv * Wd[k * 3 + 1];
        p2 += hv * Wd[k * 3 + 2];
    }
    #pragma unroll
    for (int off = 32; off > 0; off >>= 1) {
        p0 += __shfl_down(p0, off);
        p1 += __shfl_down(p1, off);
        p2 += __shfl_down(p2, off);
    }
    if (ln == 0) {
        float l0 = p0 + bd[0], l1 = p1 + bd[1], l2 = p2 + bd[2];
        float m = fmaxf(l0, fmaxf(l1, l2));
        float lse = m + logf(__expf(l0 - m) + __expf(l1 - m) + __expf(l2 - m));
        int lab = labels[b];
        float sel = (lab == 0) ? l0 : ((lab == 1) ? l1 : l2);
        float nll = lse - sel;
        out[1 + b * 3 + 0] = l0;
        out[1 + b * 3 + 1] = l1;
        out[1 + b * 3 + 2] = l2;
        atomicAdd(out, nll * (1.0f / BB));
    }
}

// ---------------------------------------------------------------------------
extern "C" void kernel_launch(void* const* d_in, const int* in_sizes, int n_in,
                              void* d_out, int out_size, void* d_ws, size_t ws_size,
                              hipStream_t stream) {
    const int*   ids  = (const int*)d_in[0];
    const int*   lens = (const int*)d_in[1];
    const int*   labs = (const int*)d_in[2];
    const float* emb  = (const float*)d_in[3];
    const float* Wl   = (const float*)d_in[4];
    const float* bl   = (const float*)d_in[5];
    const float* Wd   = (const float*)d_in[6];
    const float* bd   = (const float*)d_in[7];
    float* out = (float*)d_out;

    float*    zx   = (float*)d_ws;
    unsigned* exv  = (unsigned*)(zx + ZX_F);
    unsigned* ext  = exv + EXV_W;
    float*    cst  = (float*)(ext + EXT_W);
    float*    hfin = cst + CST_F;

    {   // zero tag table / c state / out[0]
        int n = (int)((CST_F + 255) / 256);
        init_kernel<<<n, 256, 0, stream>>>(ext, cst, out);
    }
    for (int c = 0; c < NCHUNK; ++c) {
        int t0 = c * CHUNK;
        zx_gemm<<<dim3(32, 15), 256, 0, stream>>>(emb, ids, Wl, bl, zx, t0);
        lstm_rec<<<GR * GC, 256, 0, stream>>>(zx, Wl, lens, exv, ext, cst, hfin, t0);
    }
    cls_kernel<<<BB, 64, 0, stream>>>(hfin, Wd, bd, labs, out);
}

// Round 5
// 2284.312 us; speedup vs baseline: 454.8245x; 1.4454x over previous
//
#include <hip/hip_runtime.h>
#include <hip/hip_bf16.h>
#include <math.h>

// Problem constants
#define VV   32000
#define DD   300
#define HU   300
#define NC   3
#define BB   128
#define TT   512
#define N4H  1200
#define CHUNK 64
#define NCHUNK (TT / CHUNK)

// Recurrent kernel partition (round-0 proven structure)
#define GC   15   // col groups (units)
#define GR   16   // row groups
#define RPW  8    // rows per WG (BB/GR)
#define UPW  20   // units per WG (HU/GC)
#define KSW  96   // k-window per wave (4 waves x 96 covers 300 w/ zero pad)
#define HLB_STRIDE 312            // h plane row stride in shorts (624B: 16B-aligned, 2-way bank alias = free)
#define HLB_SIZE   (16 * HLB_STRIDE + 32)

// Workspace layout: [zx (float)][ex (ulong, tagged h exchange)][cst][hfin]
static constexpr size_t ZX_F   = (size_t)BB * CHUNK * N4H;   // 9,830,400 floats
static constexpr size_t EX_W   = (size_t)2 * GR * RPW * HU;  // 76,800 ulongs
static constexpr size_t CST_F  = (size_t)BB * HU;            // 38,400 floats
static constexpr size_t HFIN_F = (size_t)BB * HU;            // 38,400 floats

typedef __attribute__((ext_vector_type(8))) short bf16x8;
typedef __attribute__((ext_vector_type(8))) _Float16 f16x8;
typedef __attribute__((ext_vector_type(4))) float f32x4;
typedef unsigned long long ull;

__device__ __forceinline__ short f2bf(float f) {
    unsigned u = __float_as_uint(f);
    u += 0x7fff + ((u >> 16) & 1);   // round-to-nearest-even
    return (short)(u >> 16);
}
__device__ __forceinline__ short f2h(float f) {   // float -> f16 bits (RTNE)
    _Float16 h = (_Float16)f;
    return *(short*)&h;
}
__device__ __forceinline__ float h2f(short s) {
    _Float16 h = *(_Float16*)&s;
    return (float)h;
}
__device__ __forceinline__ float sigm(float x) { return 1.f / (1.f + __expf(-x)); }
__device__ __forceinline__ float tanh_(float x) { return 1.f - 2.f / (__expf(2.f * x) + 1.f); }

// ---------------------------------------------------------------------------
// init: zero exchange tags, c state, out[0]  (ws is poisoned 0xAA every launch)
// ---------------------------------------------------------------------------
__global__ void init_kernel(ull* __restrict__ ex, float* __restrict__ cst,
                            float* __restrict__ out) {
    size_t i = (size_t)blockIdx.x * 256 + threadIdx.x;
    if (i < EX_W) ex[i] = 0ull;
    if (i < CST_F) cst[i] = 0.f;
    if (i == 0) out[0] = 0.f;
}

// ---------------------------------------------------------------------------
// Phase 1: zx[b][tc][n] = emb[ids[b][t0+tc]] @ W_lstm[0:300] + b_lstm   (bf16 MFMA)
// WG tile: M=256 rows, N=80 cols, K=320 (300 zero-padded). 4 waves, wave = 64x80.
// grid = (8192/256, 1200/80) = (32, 15)   [round-0, verified]
// ---------------------------------------------------------------------------
__global__ __launch_bounds__(256) void zx_gemm(
    const float* __restrict__ emb, const int* __restrict__ ids,
    const float* __restrict__ Wl, const float* __restrict__ bl,
    float* __restrict__ zx, int t0)
{
    __shared__ short A_l[256 * 40];   // [row][k] pad 32->40 shorts
    __shared__ short B_l[80 * 40];    // [col][k] (transposed)
    __shared__ int   ids_l[256];

    const int tid = threadIdx.x;
    const int m0  = blockIdx.x * 256;
    const int n0  = blockIdx.y * 80;
    const int wv  = tid >> 6, ln = tid & 63;

    {   // per-row embedding id
        int m = m0 + tid;
        int b = m >> 6, tc = m & (CHUNK - 1);
        ids_l[tid] = ids[b * TT + t0 + tc];
    }

    f32x4 acc[4][5];
    for (int i = 0; i < 4; ++i)
        for (int j = 0; j < 5; ++j)
            acc[i][j] = (f32x4){0.f, 0.f, 0.f, 0.f};

    for (int k0 = 0; k0 < 320; k0 += 32) {
        __syncthreads();
        // stage A: 256 rows x 32 k, one row per thread (float4 x8, guard k<300)
        {
            const float* src = emb + (size_t)ids_l[tid] * DD;
            #pragma unroll
            for (int q = 0; q < 8; ++q) {
                int kg = k0 + q * 4;
                float4 v;
                if (kg < DD) v = *(const float4*)(src + kg);
                else         v = make_float4(0.f, 0.f, 0.f, 0.f);
                short4 s; s.x = f2bf(v.x); s.y = f2bf(v.y); s.z = f2bf(v.z); s.w = f2bf(v.w);
                *(short4*)&A_l[tid * 40 + q * 4] = s;
            }
        }
        // stage B (transposed): 80 cols x 32 k. thread: kk=tid>>3, 10 cols each
        {
            int kk = tid >> 3;
            int c0 = (tid & 7) * 10;
            int kg = k0 + kk;
            #pragma unroll
            for (int c = 0; c < 10; ++c) {
                float v = (kg < DD) ? Wl[(size_t)kg * N4H + n0 + c0 + c] : 0.f;
                B_l[(c0 + c) * 40 + kk] = f2bf(v);
            }
        }
        __syncthreads();
        // fragments + MFMA. A[m=lane&15][k=quad*8+j], B[k=quad*8+j][n=lane&15]
        const int koff = (ln >> 4) * 8;
        bf16x8 afr[4], bfr[5];
        #pragma unroll
        for (int mt = 0; mt < 4; ++mt) {
            int row = wv * 64 + mt * 16 + (ln & 15);
            afr[mt] = *(const bf16x8*)&A_l[row * 40 + koff];
        }
        #pragma unroll
        for (int nt = 0; nt < 5; ++nt) {
            int col = nt * 16 + (ln & 15);
            bfr[nt] = *(const bf16x8*)&B_l[col * 40 + koff];
        }
        #pragma unroll
        for (int mt = 0; mt < 4; ++mt)
            #pragma unroll
            for (int nt = 0; nt < 5; ++nt)
                acc[mt][nt] = __builtin_amdgcn_mfma_f32_16x16x32_bf16(
                    afr[mt], bfr[nt], acc[mt][nt], 0, 0, 0);
    }
    // epilogue: C row=(lane>>4)*4+reg, col=lane&15; add bias
    #pragma unroll
    for (int mt = 0; mt < 4; ++mt) {
        #pragma unroll
        for (int nt = 0; nt < 5; ++nt) {
            #pragma unroll
            for (int rg = 0; rg < 4; ++rg) {
                int row = m0 + wv * 64 + mt * 16 + (ln >> 4) * 4 + rg;
                int col = n0 + nt * 16 + (ln & 15);
                zx[(size_t)row * N4H + col] = acc[mt][nt][rg] + bl[col];
            }
        }
    }
}

// ---------------------------------------------------------------------------
// Phase 2: persistent recurrent kernel. 240 WGs = 16 row-groups x 15 col-groups.
// ROUND-0 PROVEN STRUCTURE (R12: sentinel-gated polling, per-word tags,
// parity-2 buffers, single barrier per step). R17's ONLY change: producer-side
// f16 hi/lo payload packing [tag:32 | lo:16 | hi:16] — proven correct in
// R13/R14 (both passed absmax 4.88e-4 with this encoding). Consumers
// bit-extract instead of f16-convert per accepted word.
//
// Recurrent GEMM: F16 MFMA with h-side split (absmax at 4.88e-4 output floor):
//   z = (h_hi + h_lo) @ W_f16,  h_hi = f16(h), h_lo = f16(h - h_hi)
// W_h f16 fragments live in LDS, fragment-ordered (R10). Per-wave K-window
// waiting + single barrier per step (R11). Sentinel-gated polling (R12).
//
// Tag-ABA safety (transitive, per-wave): publish(s+2) > barrier(s+1)
// > all 4 waves detected tags s+1 over window-union = all 15 producers'
// s+1 publishes >= every consumer's step-s reads.
//
// NaN guard (R6): both h planes zeroed IN FULL once per dispatch, so wave 3's
// A reads of cols 300..319 are exact 0 (B=0 there; 0*0=0).
// ---------------------------------------------------------------------------
__global__ __launch_bounds__(256, 1) void lstm_rec(
    const float* __restrict__ zx, const float* __restrict__ Wl,
    const int* __restrict__ lens, ull* __restrict__ ex,
    float* __restrict__ cst, float* __restrict__ hfin, int t0)
{
    const int tid = threadIdx.x;
    const int wv  = tid >> 6, ln = tid & 63;
    const int rg  = blockIdx.x % GR;
    const int cgi = blockIdx.x / GR;
    const int r0  = rg * RPW;
    const int u0  = cgi * UPW;
    const int m   = ln & 15;           // MFMA row / col-in-tile
    const int quad = ln >> 4;

    // producers overlapping wave wv's K-window [96wv, 96wv+96)
    const int pstart_tbl[4] = {0, 4, 9, 14};
    const int np_tbl[4]     = {5, 6, 6, 1};
    const int pstart = pstart_tbl[wv];
    const int np     = np_tbl[wv];

    __shared__ short h_hi[HLB_SIZE];        // f16 hi plane of h_{t-1}
    __shared__ short h_lo[HLB_SIZE];        // f16 lo plane of h_{t-1}
    __shared__ float zp[2][4][RPW][84];     // parity x wave k-partials (pad 80->84)
    __shared__ short w_l[4 * 15 * 64 * 8];  // f16 W_h fragments, frag-ordered

    // ---- one-time: pack W_h f16 B-fragments into LDS ----
    // B[k=quad*8+j][n=lane&15]; frag f = s*5+nt covers kstep s, ntile nt.
    #pragma unroll
    for (int s = 0; s < 3; ++s) {
        #pragma unroll
        for (int nt = 0; nt < 5; ++nt) {
            int c    = nt * 16 + m;            // 0..79 within WG cols
            int gate = c / 20;
            int wcol = 300 * gate + u0 + (c % 20);
            f16x8 b;
            #pragma unroll
            for (int j = 0; j < 8; ++j) {
                int k = KSW * wv + 32 * s + quad * 8 + j;
                float v = (k < HU) ? Wl[(size_t)(DD + k) * N4H + wcol] : 0.f;
                b[j] = (_Float16)v;
            }
            *(f16x8*)&w_l[(((wv * 15) + (s * 5 + nt)) * 64 + ln) * 8] = b;
        }
    }
    const int nks = (wv == 3) ? 1 : 3;   // wave 3: only kstep 0 has real k

    // zero BOTH h planes in full once per dispatch (NaN guard + h0 = 0)
    for (int i = tid; i < HLB_SIZE; i += 256) { h_hi[i] = 0; h_lo[i] = 0; }

    // gate role (tid < 160): u = tid%20, r = tid/20; c/h_old in registers
    const int g_u = tid % UPW, g_r = tid / UPW;
    const bool gl = (tid < RPW * UPW);
    float c_reg = 0.f, ho_reg = 0.f;
    int mylen = 0;
    if (gl) {
        c_reg = cst[(size_t)(r0 + g_r) * HU + u0 + g_u];
        mylen = lens[r0 + g_r];
        if (t0 > 0) {   // reload own h_{t0-1} (tag t0, parity t0&1) from last dispatch
            ull v = __hip_atomic_load(
                ex + (((size_t)(t0 & 1) * GR + rg) * RPW + g_r) * HU + u0 + g_u,
                __ATOMIC_RELAXED, __HIP_MEMORY_SCOPE_AGENT);
            unsigned d = (unsigned)v;
            ho_reg = h2f((short)(d & 0xFFFFu)) + h2f((short)(d >> 16));
        }
    }
    __syncthreads();   // h-plane zero + w_l pack visible before first step

    for (int tc = 0; tc < CHUNK; ++tc) {
        const int t = t0 + tc;
        const int par = t & 1;

        // prefetch zx for this step (independent of h)
        float z_pre[4];
        if (gl) {
            const float* zrow = zx + ((size_t)(r0 + g_r) * CHUNK + tc) * N4H;
            #pragma unroll
            for (int gg = 0; gg < 4; ++gg)
                z_pre[gg] = zrow[300 * gg + u0 + g_u];
        }

        // ---- per-wave stage of OWN K-window stripe (no barrier after) ----
        if (t > 0) {
            const ull* exb = ex + ((size_t)par * GR + rg) * (RPW * HU);

            // phase 1: sentinel spin — lane l polls producer pstart+l (word
            // r=0, u=20p). Cheap (<=6 lines/wave/sweep vs 96 for a full pass).
            if (ln < np) {
                const ull* sp = exb + (pstart + ln) * UPW;
                while ((int)(__hip_atomic_load(sp, __ATOMIC_RELAXED,
                             __HIP_MEMORY_SCOPE_AGENT) >> 32) < t)
                    __builtin_amdgcn_s_sleep(1);
            }

            // phase 2+3: full stripe pass (typically 1 sweep) + straggler poll
            if (wv < 3) {
                // 768 words: i = ln + 64k, r = i/96, u = 96*wv + i%96
                unsigned pend = 0xFFFu;
                do {
                    ull v[12];
                    #pragma unroll
                    for (int k = 0; k < 12; ++k)
                        if ((pend >> k) & 1) {
                            int i = ln + (k << 6);
                            int r = i / 96, u = KSW * wv + (i % 96);
                            v[k] = __hip_atomic_load(exb + r * HU + u,
                                                     __ATOMIC_RELAXED,
                                                     __HIP_MEMORY_SCOPE_AGENT);
                        }
                    unsigned got = 0;
                    #pragma unroll
                    for (int k = 0; k < 12; ++k) {
                        if (((pend >> k) & 1) && (int)(v[k] >> 32) >= t) {
                            int i = ln + (k << 6);
                            int r = i / 96, u = KSW * wv + (i % 96);
                            int idx = r * HLB_STRIDE + u;
                            unsigned d = (unsigned)v[k];
                            h_hi[idx] = (short)(d & 0xFFFFu);
                            h_lo[idx] = (short)(d >> 16);
                            got |= 1u << k;
                        }
                    }
                    pend &= ~got;
                    if (pend) __builtin_amdgcn_s_sleep(1);
                } while (pend);
            } else {
                // 96 words: i = ln + 64k (i<96), r = i/12, u = 288 + i%12
                unsigned pend = (ln < 32) ? 0x3u : 0x1u;
                do {
                    ull v[2];
                    #pragma unroll
                    for (int k = 0; k < 2; ++k)
                        if ((pend >> k) & 1) {
                            int i = ln + (k << 6);
                            int r = i / 12, u = 288 + (i % 12);
                            v[k] = __hip_atomic_load(exb + r * HU + u,
                                                     __ATOMIC_RELAXED,
                                                     __HIP_MEMORY_SCOPE_AGENT);
                        }
                    unsigned got = 0;
                    #pragma unroll
                    for (int k = 0; k < 2; ++k) {
                        if (((pend >> k) & 1) && (int)(v[k] >> 32) >= t) {
                            int i = ln + (k << 6);
                            int r = i / 12, u = 288 + (i % 12);
                            int idx = r * HLB_STRIDE + u;
                            unsigned d = (unsigned)v[k];
                            h_hi[idx] = (short)(d & 0xFFFFu);
                            h_lo[idx] = (short)(d >> 16);
                            got |= 1u << k;
                        }
                    }
                    pend &= ~got;
                    if (pend) __builtin_amdgcn_s_sleep(1);
                } while (pend);
            }
        }

        // ---- MFMA on own stripe: A hi/lo from LDS, B f16 from LDS ----
        f32x4 acc[5];
        #pragma unroll
        for (int nt = 0; nt < 5; ++nt) acc[nt] = (f32x4){0.f, 0.f, 0.f, 0.f};
        for (int s = 0; s < nks; ++s) {
            const int aoff = m * HLB_STRIDE + KSW * wv + 32 * s + quad * 8;
            f16x8 ah = *(const f16x8*)&h_hi[aoff];
            f16x8 al = *(const f16x8*)&h_lo[aoff];
            f16x8 bfr[5];
            #pragma unroll
            for (int nt = 0; nt < 5; ++nt)
                bfr[nt] = *(const f16x8*)&w_l[(((wv * 15) + (s * 5 + nt)) * 64 + ln) * 8];
            #pragma unroll
            for (int nt = 0; nt < 5; ++nt)
                acc[nt] = __builtin_amdgcn_mfma_f32_16x16x32_f16(
                    ah, bfr[nt], acc[nt], 0, 0, 0);
            #pragma unroll
            for (int nt = 0; nt < 5; ++nt)
                acc[nt] = __builtin_amdgcn_mfma_f32_16x16x32_f16(
                    al, bfr[nt], acc[nt], 0, 0, 0);
        }
        // C: row=quad*4+reg (lanes 0-31 -> rows 0-7), col=nt*16+m
        if (ln < 32) {
            #pragma unroll
            for (int nt = 0; nt < 5; ++nt)
                #pragma unroll
                for (int r4 = 0; r4 < 4; ++r4)
                    zp[par][wv][quad * 4 + r4][nt * 16 + m] = acc[nt][r4];
        }
        __syncthreads();   // the ONE barrier: zp(t) visible to gate lanes

        // ---- reduce 4 partials + gates + tagged publish (160 threads) ----
        if (gl) {
            const int b = r0 + g_r;
            float z4[4];
            #pragma unroll
            for (int gg = 0; gg < 4; ++gg) {
                int cidx = gg * UPW + g_u;
                z4[gg] = z_pre[gg] + zp[par][0][g_r][cidx] + zp[par][1][g_r][cidx]
                                   + zp[par][2][g_r][cidx] + zp[par][3][g_r][cidx];
            }
            float ig = sigm(z4[0]);
            float jg = tanh_(z4[1]);
            float fg = sigm(z4[2] + 1.0f);   // FORGET_BIAS
            float og = sigm(z4[3]);
            float c_new = c_reg * fg + ig * jg;
            float h_new = tanh_(c_new) * og;
            bool upd = (t < mylen);
            ho_reg = upd ? h_new : ho_reg;
            c_reg  = upd ? c_new : c_reg;
            // publish h_t (tag t+1, parity (t+1)&1), producer-side hi/lo split:
            // [tag:32 | lo:16 | hi:16] — fire & forget (R17; proven in R13/R14)
            short hhi = f2h(ho_reg);
            short hlo = f2h(ho_reg - h2f(hhi));
            ull pk = ((ull)(unsigned)(t + 1) << 32)
                   | ((ull)(unsigned short)hlo << 16) | (ull)(unsigned short)hhi;
            __hip_atomic_store(
                ex + (((size_t)((t + 1) & 1) * GR + rg) * RPW + g_r) * HU + u0 + g_u,
                pk, __ATOMIC_RELAXED, __HIP_MEMORY_SCOPE_AGENT);
            if (tc == CHUNK - 1) hfin[(size_t)b * HU + u0 + g_u] = ho_reg;
        }
        // no trailing barrier: per-wave detect + the single barrier order all
        // h-stripe and zp reuse (see header proof).
    }
    if (gl) cst[(size_t)(r0 + g_r) * HU + u0 + g_u] = c_reg;
}

// ---------------------------------------------------------------------------
// Phase 3: logits = h_final @ W_dense + b_dense; log-softmax NLL; mean loss.
// One wave per batch row.
// ---------------------------------------------------------------------------
__global__ __launch_bounds__(64) void cls_kernel(
    const float* __restrict__ hfin, const float* __restrict__ Wd,
    const float* __restrict__ bd, const int* __restrict__ labels,
    float* __restrict__ out)
{
    const int b = blockIdx.x;
    const int ln = threadIdx.x;
    const float* h = hfin + (size_t)b * HU;
    float p0 = 0.f, p1 = 0.f, p2 = 0.f;
    for (int k = ln; k < HU; k += 64) {
        float hv = h[k];
        p0 += hv * Wd[k * 3 + 0];
        p1 += hv * Wd[k * 3 + 1];
        p2 += hv * Wd[k * 3 + 2];
    }
    #pragma unroll
    for (int off = 32; off > 0; off >>= 1) {
        p0 += __shfl_down(p0, off);
        p1 += __shfl_down(p1, off);
        p2 += __shfl_down(p2, off);
    }
    if (ln == 0) {
        float l0 = p0 + bd[0], l1 = p1 + bd[1], l2 = p2 + bd[2];
        float m = fmaxf(l0, fmaxf(l1, l2));
        float lse = m + logf(__expf(l0 - m) + __expf(l1 - m) + __expf(l2 - m));
        int lab = labels[b];
        float sel = (lab == 0) ? l0 : ((lab == 1) ? l1 : l2);
        float nll = lse - sel;
        out[1 + b * 3 + 0] = l0;
        out[1 + b * 3 + 1] = l1;
        out[1 + b * 3 + 2] = l2;
        atomicAdd(out, nll * (1.0f / BB));
    }
}

// ---------------------------------------------------------------------------
extern "C" void kernel_launch(void* const* d_in, const int* in_sizes, int n_in,
                              void* d_out, int out_size, void* d_ws, size_t ws_size,
                              hipStream_t stream) {
    const int*   ids  = (const int*)d_in[0];
    const int*   lens = (const int*)d_in[1];
    const int*   labs = (const int*)d_in[2];
    const float* emb  = (const float*)d_in[3];
    const float* Wl   = (const float*)d_in[4];
    const float* bl   = (const float*)d_in[5];
    const float* Wd   = (const float*)d_in[6];
    const float* bd   = (const float*)d_in[7];
    float* out = (float*)d_out;

    float* zx   = (float*)d_ws;
    ull*   ex   = (ull*)(zx + ZX_F);
    float* cst  = (float*)(ex + EX_W);
    float* hfin = cst + CST_F;

    {   // zero exchange tags / c state / out[0]
        int n = (int)((EX_W + 255) / 256);
        init_kernel<<<n, 256, 0, stream>>>(ex, cst, out);
    }
    for (int c = 0; c < NCHUNK; ++c) {
        int t0 = c * CHUNK;
        zx_gemm<<<dim3(32, 15), 256, 0, stream>>>(emb, ids, Wl, bl, zx, t0);
        lstm_rec<<<GR * GC, 256, 0, stream>>>(zx, Wl, lens, ex, cst, hfin, t0);
    }
    cls_kernel<<<BB, 64, 0, stream>>>(hfin, Wd, bd, labs, out);
}